// Round 3
// baseline (2275.049 us; speedup 1.0000x reference)
//
#include <hip/hip_runtime.h>
#include <math.h>

#define NV 196608
#define NDEG 9
#define NC 64
#define NK 8
#define TILE 64
#define GRID 512
#define TPB 6                  // tiles per block: 512*6*64 = 196608 rows
#define LDA 72                 // padded LDS row stride (shorts) for the A tile
static constexpr float EPS = 1e-5f;

typedef __attribute__((ext_vector_type(8))) short bf16x8;
typedef __attribute__((ext_vector_type(4))) short bf16x4;
typedef __attribute__((ext_vector_type(4))) float f32x4;

// float -> bf16 bits, round-to-nearest-even (finite inputs)
__device__ __forceinline__ short f2bf(float f) {
    unsigned u = __float_as_uint(f);
    unsigned r = (u + 0x7fffu + ((u >> 16) & 1u)) >> 16;
    return (short)r;
}

// exact mish: h * tanh(softplus(h)); tanh(ln(p)) = (p^2-1)/(p^2+1), p = 1+e^h
__device__ __forceinline__ float mish_f(float h) {
    float t = __expf(fminf(h, 20.f));
    float p = 1.f + t;
    float p2 = p * p;
    return h * ((p2 - 1.f) / (p2 + 1.f));
}

// Device-wide barrier: per-phase monotone counter (zeroed by memset each launch).
// Safe because grid==512 is exactly co-resident under __launch_bounds__(256,2).
__device__ __forceinline__ void grid_barrier(unsigned* cnt, int phase) {
    __syncthreads();
    if (threadIdx.x == 0) {
        __threadfence();                       // release: drain our global writes
        atomicAdd(&cnt[phase], 1u);            // device-scope by default
        while (atomicAdd(&cnt[phase], 0u) < (unsigned)GRID)
            __builtin_amdgcn_s_sleep(2);
        __threadfence();                       // acquire: invalidate stale cache
    }
    __syncthreads();
}

// Stage W_k (64x64 fp32, layout [i][o]) -> LDS bf16 transposed Wt[o][i],
// XOR-swizzled in 8-short chunks so b128 reads are conflict-free.
__device__ __forceinline__ void stage_W(const float* __restrict__ wk, short* Wt) {
    #pragma unroll
    for (int h = 0; h < 2; ++h) {
        int ci = threadIdx.x + h * 256;        // 512 chunks of 8 shorts
        int r = ci >> 3;                       // out channel o
        int c = ci & 7;                        // input-chunk index
        bf16x8 w;
        #pragma unroll
        for (int j = 0; j < 8; ++j)
            w[j] = f2bf(wk[(c * 8 + j) * NC + r]);
        *(bf16x8*)&Wt[r * NC + (c ^ (r & 7)) * 8] = w;
    }
}

// acc[nt] += At(own 16 rows) @ Wt ; A unswizzled (LDA pad), B xor-swizzled.
__device__ __forceinline__ void mfma_tile(const short* At, const short* Wt,
                                          f32x4* acc, int wave, int m16, int qq) {
    bf16x8 a0 = *(const bf16x8*)&At[(wave * 16 + m16) * LDA + qq * 8];
    bf16x8 a1 = *(const bf16x8*)&At[(wave * 16 + m16) * LDA + 32 + qq * 8];
    #pragma unroll
    for (int nt = 0; nt < 4; ++nt) {
        int r = nt * 16 + m16;
        bf16x8 b0 = *(const bf16x8*)&Wt[r * NC + ((qq) ^ (m16 & 7)) * 8];
        bf16x8 b1 = *(const bf16x8*)&Wt[r * NC + ((qq + 4) ^ (m16 & 7)) * 8];
        acc[nt] = __builtin_amdgcn_mfma_f32_16x16x32_bf16(a0, b0, acc[nt], 0, 0, 0);
        acc[nt] = __builtin_amdgcn_mfma_f32_16x16x32_bf16(a1, b1, acc[nt], 0, 0, 0);
    }
}

__global__ void __launch_bounds__(256, 2) fused_cheb(
    const float* __restrict__ x, const int* __restrict__ cols,
    const float* __restrict__ vals, const float* __restrict__ gamma,
    const float* __restrict__ beta, const float* __restrict__ weight,
    const float* __restrict__ bias, float* __restrict__ stats,
    unsigned* __restrict__ barcnt, float* __restrict__ bufA,
    float* __restrict__ bufB, float* __restrict__ out)
{
    __shared__ short Wt[NC * NC];       // 8 KB: current W_k
    __shared__ short At[TILE * LDA];    // 9.2 KB: bf16 x-tile (+stats scratch)

    const int tid  = threadIdx.x;
    const int lane = tid & 63;
    const int wave = tid >> 6;
    const int c4   = lane & 15;         // float4 column
    const int rg   = lane >> 4;         // row-in-group
    const int m16  = lane & 15;         // mfma row lane
    const int qq   = lane >> 4;         // mfma quad

    // ---------------- phase 0: BN batch stats ----------------
    const float4* x4 = (const float4*)x;
    float4 s = {0.f, 0.f, 0.f, 0.f}, ss = {0.f, 0.f, 0.f, 0.f};
    for (int i = blockIdx.x * 256 + tid; i < NV * (NC / 4); i += GRID * 256) {
        float4 v = x4[i];
        s.x += v.x; s.y += v.y; s.z += v.z; s.w += v.w;
        ss.x += v.x * v.x; ss.y += v.y * v.y; ss.z += v.z * v.z; ss.w += v.w * v.w;
    }
    #pragma unroll
    for (int off = 16; off <= 32; off <<= 1) {
        s.x += __shfl_xor(s.x, off);  s.y += __shfl_xor(s.y, off);
        s.z += __shfl_xor(s.z, off);  s.w += __shfl_xor(s.w, off);
        ss.x += __shfl_xor(ss.x, off); ss.y += __shfl_xor(ss.y, off);
        ss.z += __shfl_xor(ss.z, off); ss.w += __shfl_xor(ss.w, off);
    }
    float* red = (float*)At;
    if (lane < 16) {
        float* p = red + (wave * 16 + c4) * 8;
        p[0] = s.x; p[1] = s.y; p[2] = s.z; p[3] = s.w;
        p[4] = ss.x; p[5] = ss.y; p[6] = ss.z; p[7] = ss.w;
    }
    __syncthreads();
    if (tid < 16) {
        #pragma unroll
        for (int j = 0; j < 8; ++j) {
            float a = red[(0 * 16 + tid) * 8 + j] + red[(1 * 16 + tid) * 8 + j] +
                      red[(2 * 16 + tid) * 8 + j] + red[(3 * 16 + tid) * 8 + j];
            int ch = tid * 4 + (j & 3);
            atomicAdd(&stats[(j < 4) ? ch : 64 + ch], a);
        }
    }
    grid_barrier(barcnt, 0);

    // ---------------- BN coefficients (4 channels per lane) ----------------
    float4 sc, sh;
    {
        float4 su = ((const float4*)stats)[c4];
        float4 sq = ((const float4*)stats)[16 + c4];
        float4 g4 = ((const float4*)gamma)[c4];
        float4 b4 = ((const float4*)beta)[c4];
        #define BNC(comp) { float mu = su.comp * (1.f / NV);                     \
                            float va = sq.comp * (1.f / NV) - mu * mu;           \
                            float rs = rsqrtf(va + EPS);                         \
                            sc.comp = g4.comp * rs;                              \
                            sh.comp = b4.comp - mu * sc.comp; }
        BNC(x) BNC(y) BNC(z) BNC(w)
        #undef BNC
    }

    // ---------------- k = 0: BN + Mish -> bufA, acc = x0 @ W0 ----------------
    f32x4 acc[TPB][4];
    #pragma unroll
    for (int t = 0; t < TPB; ++t)
        #pragma unroll
        for (int nt = 0; nt < 4; ++nt)
            acc[t][nt] = (f32x4){0.f, 0.f, 0.f, 0.f};

    stage_W(weight, Wt);
    __syncthreads();

    float4* bufA4 = (float4*)bufA;
    #pragma unroll
    for (int t = 0; t < TPB; ++t) {
        int tile0 = (blockIdx.x * TPB + t) * TILE;
        #pragma unroll
        for (int it = 0; it < 4; ++it) {
            int rloc = wave * 16 + it * 4 + rg;
            int v = tile0 + rloc;
            float4 h = x4[v * 16 + c4];
            float4 m;
            m.x = mish_f(h.x * sc.x + sh.x);
            m.y = mish_f(h.y * sc.y + sh.y);
            m.z = mish_f(h.z * sc.z + sh.z);
            m.w = mish_f(h.w * sc.w + sh.w);
            bufA4[v * 16 + c4] = m;
            bf16x4 xb = { f2bf(m.x), f2bf(m.y), f2bf(m.z), f2bf(m.w) };
            *(bf16x4*)&At[rloc * LDA + 4 * c4] = xb;
        }
        mfma_tile(At, Wt, acc[t], wave, m16, qq);
    }

    // ---------------- k = 1..7: Chebyshev steps ----------------
    #pragma unroll 1
    for (int k = 1; k < NK; ++k) {
        grid_barrier(barcnt, k);          // x_{k-1} globally complete
        stage_W(weight + k * NC * NC, Wt);
        __syncthreads();

        const float4* src4 = (const float4*)((k & 1) ? bufA : bufB); // x_{k-1}
        float4*       dst4 = (float4*)((k & 1) ? bufB : bufA);       // x_{k-2} -> x_k
        const bool first = (k == 1);

        #pragma unroll
        for (int t = 0; t < TPB; ++t) {
            int tile0 = (blockIdx.x * TPB + t) * TILE;
            #pragma unroll
            for (int it = 0; it < 4; ++it) {
                int rloc = wave * 16 + it * 4 + rg;
                int v = tile0 + rloc;
                const int* cp = cols + v * NDEG;
                const float* vp = vals + v * NDEG;
                float4 sg = {0.f, 0.f, 0.f, 0.f};
                #pragma unroll
                for (int j = 0; j < NDEG; ++j) {
                    int cj = cp[j];
                    float aj = vp[j];
                    float4 g = src4[cj * 16 + c4];  // 256 B coalesced per row
                    sg.x += aj * g.x; sg.y += aj * g.y;
                    sg.z += aj * g.z; sg.w += aj * g.w;
                }
                float4 xn;
                if (first) {
                    xn = sg;
                } else {
                    float4 p = dst4[v * 16 + c4];   // own x_{k-2}, then overwrite
                    xn.x = 2.f * sg.x - p.x; xn.y = 2.f * sg.y - p.y;
                    xn.z = 2.f * sg.z - p.z; xn.w = 2.f * sg.w - p.w;
                }
                dst4[v * 16 + c4] = xn;
                bf16x4 xb = { f2bf(xn.x), f2bf(xn.y), f2bf(xn.z), f2bf(xn.w) };
                *(bf16x4*)&At[rloc * LDA + 4 * c4] = xb;
            }
            mfma_tile(At, Wt, acc[t], wave, m16, qq);
        }
    }

    // ---------------- epilogue: out = acc + bias (written once) ----------------
    #pragma unroll
    for (int t = 0; t < TPB; ++t) {
        int tile0 = (blockIdx.x * TPB + t) * TILE;
        #pragma unroll
        for (int nt = 0; nt < 4; ++nt) {
            float bcol = bias[nt * 16 + m16];
            #pragma unroll
            for (int r = 0; r < 4; ++r) {
                int vout = tile0 + wave * 16 + qq * 4 + r;
                out[vout * NC + nt * 16 + m16] = acc[t][nt][r] + bcol;
            }
        }
    }
}

// ---------------------------------------------------------------------------
// Inputs: (x, lap_rows, lap_cols, lap_vals, gamma, beta, weight, bias).
// lap_rows redundant (row-sorted, exactly 9 nnz/row). cols delivered as int32.
// ws: stats[128] f32 | barcnt[16] u32 | pad | bufA (V*64 f32) | bufB (V*64 f32)
// ---------------------------------------------------------------------------
extern "C" void kernel_launch(void* const* d_in, const int* in_sizes, int n_in,
                              void* d_out, int out_size, void* d_ws, size_t ws_size,
                              hipStream_t stream) {
    const float* x      = (const float*)d_in[0];
    const int*   cols   = (const int*)  d_in[2];
    const float* vals   = (const float*)d_in[3];
    const float* gamma  = (const float*)d_in[4];
    const float* beta   = (const float*)d_in[5];
    const float* weight = (const float*)d_in[6];
    const float* bias   = (const float*)d_in[7];
    float* out = (float*)d_out;

    float*    wsf    = (float*)d_ws;
    float*    stats  = wsf;                         // 128 floats
    unsigned* barcnt = (unsigned*)(wsf + 128);      // 16 counters
    float*    bufA   = wsf + 256;                   // 1 KiB offset
    float*    bufB   = bufA + (size_t)NV * NC;

    hipMemsetAsync(wsf, 0, 1024, stream);           // zero stats + barrier counters

    fused_cheb<<<GRID, 256, 0, stream>>>(x, cols, vals, gamma, beta, weight, bias,
                                         stats, barcnt, bufA, bufB, out);
}

// Round 4
// 458.048 us; speedup vs baseline: 4.9668x; 4.9668x over previous
//
#include <hip/hip_runtime.h>
#include <math.h>

#define NV 196608
#define NDEG 9
#define NC 64
#define NK 8
#define TILE 64
#define NBLK (NV / TILE)   // 3072
#define LDA 72             // padded LDS row stride (shorts); proven conflict-free reads
static constexpr float EPS = 1e-5f;

typedef __attribute__((ext_vector_type(8))) short bf16x8;
typedef __attribute__((ext_vector_type(4))) short bf16x4;
typedef __attribute__((ext_vector_type(4))) float f32x4;

// float -> bf16 bits, round-to-nearest-even (finite inputs)
__device__ __forceinline__ short f2bf(float f) {
    unsigned u = __float_as_uint(f);
    unsigned r = (u + 0x7fffu + ((u >> 16) & 1u)) >> 16;
    return (short)r;
}
__device__ __forceinline__ float bf2f(short h) {
    return __uint_as_float(((unsigned)(unsigned short)h) << 16);
}

// exact mish: h * tanh(softplus(h)); tanh(ln(p)) = (p^2-1)/(p^2+1), p = 1+e^h
__device__ __forceinline__ float mish_f(float h) {
    float t = __expf(fminf(h, 20.f));
    float p = 1.f + t;
    float p2 = p * p;
    return h * ((p2 - 1.f) / (p2 + 1.f));
}

// ---------------------------------------------------------------------------
// BN batch stats: per-channel sum / sumsq, float4 loads (round-2 proven).
// ---------------------------------------------------------------------------
__global__ void __launch_bounds__(256) stats_kernel(const float* __restrict__ x,
                                                    float* __restrict__ stats) {
    const float4* x4 = (const float4*)x;
    int t = blockIdx.x * 256 + threadIdx.x;
    int stride = gridDim.x * 256;
    float4 s = {0.f, 0.f, 0.f, 0.f}, ss = {0.f, 0.f, 0.f, 0.f};
    for (int i = t; i < NV * (NC / 4); i += stride) {
        float4 v = x4[i];
        s.x += v.x; s.y += v.y; s.z += v.z; s.w += v.w;
        ss.x += v.x * v.x; ss.y += v.y * v.y; ss.z += v.z * v.z; ss.w += v.w * v.w;
    }
    __shared__ float4 ls[256], lss[256];
    ls[threadIdx.x] = s;
    lss[threadIdx.x] = ss;
    __syncthreads();
    if (threadIdx.x < 64) {
        int ch = threadIdx.x;
        int g = ch >> 2, comp = ch & 3;
        float a = 0.f, b = 0.f;
        #pragma unroll
        for (int k = 0; k < 16; ++k) {
            float4 v1 = ls[k * 16 + g];
            float4 v2 = lss[k * 16 + g];
            a += (comp == 0) ? v1.x : (comp == 1) ? v1.y : (comp == 2) ? v1.z : v1.w;
            b += (comp == 0) ? v2.x : (comp == 1) ? v2.y : (comp == 2) ? v2.z : v2.w;
        }
        atomicAdd(&stats[ch], a);
        atomicAdd(&stats[64 + ch], b);
    }
}

// ---------------------------------------------------------------------------
// W pre-transpose: Wb[k][o][i] = bf16(weight[k][i][o]). 32768 elements.
// ---------------------------------------------------------------------------
__global__ void __launch_bounds__(256) wconv_kernel(const float* __restrict__ w,
                                                    unsigned short* __restrict__ Wb) {
    int idx = blockIdx.x * 256 + threadIdx.x;      // 128 blocks * 256 = 32768
    int i = idx & 63, o = (idx >> 6) & 63, k = idx >> 12;
    Wb[idx] = (unsigned short)f2bf(w[k * 4096 + i * 64 + o]);
}

// ---------------------------------------------------------------------------
// k=0: BN apply + Mish -> basis slot 0 (bf16). Pure elementwise.
// ---------------------------------------------------------------------------
__global__ void __launch_bounds__(256) bn_mish_k0(
    const float* __restrict__ x, const float* __restrict__ stats,
    const float* __restrict__ gamma, const float* __restrict__ beta,
    unsigned short* __restrict__ dst) {
    int lane = threadIdx.x & 63;
    int wave = threadIdx.x >> 6;
    int c4 = lane & 15, rg = lane >> 4;
    int tile0 = blockIdx.x * TILE;

    float4 sc, sh;
    {
        float4 su = ((const float4*)stats)[c4];
        float4 sq = ((const float4*)stats)[16 + c4];
        float4 g4 = ((const float4*)gamma)[c4];
        float4 b4 = ((const float4*)beta)[c4];
        #define BNC(comp) { float mu = su.comp * (1.f / NV);                     \
                            float va = sq.comp * (1.f / NV) - mu * mu;           \
                            float rs = rsqrtf(va + EPS);                         \
                            sc.comp = g4.comp * rs;                              \
                            sh.comp = b4.comp - mu * sc.comp; }
        BNC(x) BNC(y) BNC(z) BNC(w)
        #undef BNC
    }

    const float4* x4 = (const float4*)x;
    #pragma unroll
    for (int it = 0; it < 4; ++it) {
        int v = tile0 + wave * 16 + it * 4 + rg;
        float4 h = x4[v * 16 + c4];
        float4 m;
        m.x = mish_f(h.x * sc.x + sh.x);
        m.y = mish_f(h.y * sc.y + sh.y);
        m.z = mish_f(h.z * sc.z + sh.z);
        m.w = mish_f(h.w * sc.w + sh.w);
        bf16x4 xb = { f2bf(m.x), f2bf(m.y), f2bf(m.z), f2bf(m.w) };
        *(bf16x4*)(dst + (size_t)v * NC + 4 * c4) = xb;
    }
}

// ---------------------------------------------------------------------------
// One Chebyshev step, bf16 in/out, fp32 arithmetic. Pure gather/stream:
//   s = L @ src; dst = FIRST ? s : 2*s - prev.
// 8 lanes per row (bf16x8 = 16 B/lane, 128 B/row coalesced), 16 rows/wave.
// ---------------------------------------------------------------------------
template <bool FIRST>
__global__ void __launch_bounds__(256) cheb_step(
    const int* __restrict__ cols, const float* __restrict__ vals,
    const unsigned short* __restrict__ src, const unsigned short* __restrict__ prev,
    unsigned short* __restrict__ dst) {
    int lane = threadIdx.x & 63;
    int wave = threadIdx.x >> 6;
    int c8 = lane & 7, rg = lane >> 3;
    int tile0 = blockIdx.x * TILE;

    #pragma unroll
    for (int it = 0; it < 2; ++it) {
        int v = tile0 + wave * 16 + it * 8 + rg;
        const int* cp = cols + v * NDEG;
        const float* vp = vals + v * NDEG;
        float s[8] = {0.f, 0.f, 0.f, 0.f, 0.f, 0.f, 0.f, 0.f};
        #pragma unroll
        for (int j = 0; j < NDEG; ++j) {
            int cj = cp[j];
            float aj = vp[j];
            bf16x8 g = *(const bf16x8*)(src + (size_t)cj * NC + c8 * 8);
            #pragma unroll
            for (int q = 0; q < 8; ++q) s[q] += aj * bf2f(g[q]);
        }
        bf16x8 xb;
        if (FIRST) {
            #pragma unroll
            for (int q = 0; q < 8; ++q) xb[q] = f2bf(s[q]);
        } else {
            bf16x8 p = *(const bf16x8*)(prev + (size_t)v * NC + c8 * 8);
            #pragma unroll
            for (int q = 0; q < 8; ++q) xb[q] = f2bf(2.f * s[q] - bf2f(p[q]));
        }
        *(bf16x8*)(dst + (size_t)v * NC + c8 * 8) = xb;
    }
}

// ---------------------------------------------------------------------------
// Deferred einsum over a group of resident bases:
//   out(tile) (=|+=) sum_{k in [kb,kb+kc)} basis[k%S] @ W_k  (+ bias if first)
// A/W tiles staged in LDS (LDA=72 padding; fragment reads proven 2-way-free).
// ---------------------------------------------------------------------------
__global__ void __launch_bounds__(256) gemm_bases(
    const unsigned short* __restrict__ basis, const unsigned short* __restrict__ Wb,
    const float* __restrict__ bias, float* __restrict__ out,
    int kb, int kc, int S, int first) {
    __shared__ short At[TILE * LDA];
    __shared__ short Wt[NC * LDA];
    int tid = threadIdx.x;
    int lane = tid & 63, wave = tid >> 6;
    int m16 = lane & 15, qq = lane >> 4;
    int tile0 = blockIdx.x * TILE;

    f32x4 acc[4];
    #pragma unroll
    for (int nt = 0; nt < 4; ++nt) acc[nt] = (f32x4){0.f, 0.f, 0.f, 0.f};

    #pragma unroll 1
    for (int j = 0; j < kc; ++j) {
        int k = kb + j;
        const unsigned short* bs = basis + (size_t)(k % S) * NV * NC + (size_t)tile0 * NC;
        const unsigned short* wsrc = Wb + (size_t)k * NC * NC;
        __syncthreads();                       // protect previous iter's reads
        #pragma unroll
        for (int h = 0; h < 2; ++h) {
            int ci = tid + h * 256;            // 512 chunks of 8 shorts
            int r = ci >> 3, c = ci & 7;
            *(bf16x8*)&At[r * LDA + c * 8] = *(const bf16x8*)(bs + ci * 8);
            *(bf16x8*)&Wt[r * LDA + c * 8] = *(const bf16x8*)(wsrc + ci * 8);
        }
        __syncthreads();
        bf16x8 a0 = *(const bf16x8*)&At[(wave * 16 + m16) * LDA + qq * 8];
        bf16x8 a1 = *(const bf16x8*)&At[(wave * 16 + m16) * LDA + 32 + qq * 8];
        #pragma unroll
        for (int nt = 0; nt < 4; ++nt) {
            bf16x8 b0 = *(const bf16x8*)&Wt[(nt * 16 + m16) * LDA + qq * 8];
            bf16x8 b1 = *(const bf16x8*)&Wt[(nt * 16 + m16) * LDA + 32 + qq * 8];
            acc[nt] = __builtin_amdgcn_mfma_f32_16x16x32_bf16(a0, b0, acc[nt], 0, 0, 0);
            acc[nt] = __builtin_amdgcn_mfma_f32_16x16x32_bf16(a1, b1, acc[nt], 0, 0, 0);
        }
    }

    #pragma unroll
    for (int nt = 0; nt < 4; ++nt) {
        float bcol = bias[nt * 16 + m16];
        #pragma unroll
        for (int r = 0; r < 4; ++r) {
            int vout = tile0 + wave * 16 + qq * 4 + r;
            float* po = out + (size_t)vout * NC + nt * 16 + m16;
            *po = first ? (acc[nt][r] + bcol) : (*po + acc[nt][r]);
        }
    }
}

// ---------------------------------------------------------------------------
// Inputs: (x, lap_rows, lap_cols, lap_vals, gamma, beta, weight, bias).
// lap_rows redundant (row-sorted, 9 nnz/row). Harness delivers cols as int32.
// ws: stats[128]f32 @0 | Wb bf16[8*64*64] @1 KiB | basis ring @128 KiB
// Ring size S adapts to ws_size (proven >= ~100 MB -> S >= 3; ideal S = 8).
// ---------------------------------------------------------------------------
extern "C" void kernel_launch(void* const* d_in, const int* in_sizes, int n_in,
                              void* d_out, int out_size, void* d_ws, size_t ws_size,
                              hipStream_t stream) {
    const float* x      = (const float*)d_in[0];
    const int*   cols   = (const int*)  d_in[2];
    const float* vals   = (const float*)d_in[3];
    const float* gamma  = (const float*)d_in[4];
    const float* beta   = (const float*)d_in[5];
    const float* weight = (const float*)d_in[6];
    const float* bias   = (const float*)d_in[7];
    float* out = (float*)d_out;

    char* wsb = (char*)d_ws;
    float*          stats = (float*)wsb;
    unsigned short* Wb    = (unsigned short*)(wsb + 1024);
    unsigned short* basis = (unsigned short*)(wsb + 131072);
    const size_t SLOT = (size_t)NV * NC;                     // elements per slot

    int S = (int)((ws_size - 131072) / (SLOT * sizeof(unsigned short)));
    if (S > NK) S = NK;
    if (S < 3) S = 3;   // proven workspace supports >= 3

    hipMemsetAsync(stats, 0, 1024, stream);
    wconv_kernel<<<128, 256, 0, stream>>>(weight, Wb);
    stats_kernel<<<1024, 256, 0, stream>>>(x, stats);
    bn_mish_k0<<<NBLK, 256, 0, stream>>>(x, stats, gamma, beta, basis);  // slot 0

    int kb = 0, gsize = S, first = 1;
    while (kb < NK) {
        int kc = (gsize < NK - kb) ? gsize : (NK - kb);
        for (int k = (kb == 0 ? 1 : kb); k < kb + kc; ++k) {
            const unsigned short* src = basis + (size_t)((k - 1) % S) * SLOT;
            unsigned short*       dst = basis + (size_t)(k % S) * SLOT;
            if (k == 1) {
                cheb_step<true><<<NBLK, 256, 0, stream>>>(cols, vals, src, src, dst);
            } else {
                const unsigned short* prev = basis + (size_t)((k - 2) % S) * SLOT;
                cheb_step<false><<<NBLK, 256, 0, stream>>>(cols, vals, src, prev, dst);
            }
        }
        gemm_bases<<<NBLK, 256, 0, stream>>>(basis, Wb, bias, out, kb, kc, S, first);
        first = 0;
        kb += kc;
        gsize = S - 2;
    }
}